// Round 11
// baseline (370.326 us; speedup 1.0000x reference)
//
#include <hip/hip_runtime.h>
#include <math.h>

#define N_NODES 50000
#define N_EDGES 800000
#define IN_DIM 128
#define HIDDEN 128
#define CLASSES 64
#define N2 100000      // concatenated node space: graph1 [0,50000), graph2 [50000,100000)

#define BIN_SHIFT 8    // 256 nodes per bin
#define BIN_SZ 256
#define NB 391         // ceil(100000/256)
#define NBLK 256       // edge-partition blocks for P1/P2
#define CHUNK ((2 * N_EDGES + NBLK - 1) / NBLK)

#define NSTRIP 3125    // 50000 / 16 rows per MFMA strip
#define GBLK 391       // ceil(3125 / 8 strips per block)

typedef __attribute__((ext_vector_type(8))) short bf16x8;
typedef __attribute__((ext_vector_type(4))) float f32x4;

union FragU {
    uint4 u4;
    uint2 u2[2];
    bf16x8 f;
};

static __device__ __forceinline__ float elu_f(float x) {
    return x > 0.f ? x : (expf(x) - 1.f);
}

// f32 -> bf16 (RNE) pack of two values into one uint (lo = first)
static __device__ __forceinline__ unsigned pack_bf2(float a, float b) {
    unsigned ua = __float_as_uint(a);
    ua = (ua + 0x7FFFu + ((ua >> 16) & 1u)) >> 16;
    unsigned ub = __float_as_uint(b);
    ub = (ub + 0x7FFFu + ((ub >> 16) & 1u)) >> 16;
    return ua | (ub << 16);
}

static __device__ __forceinline__ unsigned short bf1(float x) {
    unsigned u = __float_as_uint(x);
    u = (u + 0x7FFFu + ((u >> 16) & 1u)) >> 16;
    return (unsigned short)u;
}

// unpack two bf16 (packed in uint) -> float2
static __device__ __forceinline__ float2 bf2f2(unsigned u) {
    float2 r;
    r.x = __uint_as_float(u << 16);
    r.y = __uint_as_float(u & 0xFFFF0000u);
    return r;
}

// accumulate 4 bf16 dims (uint2) into float4
static __device__ __forceinline__ void acc4(float4& a, const uint2 u) {
    const float2 lo = bf2f2(u.x);
    const float2 hi = bf2f2(u.y);
    a.x += lo.x; a.y += lo.y; a.z += hi.x; a.w += hi.y;
}

// ---------------------------------------------------------------------------
// P1: per-block LDS histogram over bins. counts[bin*NBLK + blk] (bin-major).
// ---------------------------------------------------------------------------
__global__ __launch_bounds__(1024) void k_p1_count(
    const int* __restrict__ dst1, const int* __restrict__ dst2,
    int* __restrict__ counts)
{
    __shared__ int hist[NB];
    const int t = threadIdx.x, b = blockIdx.x;
    if (t < NB) hist[t] = 0;
    __syncthreads();
    const int beg = b * CHUNK;
    const int end = min(beg + CHUNK, 2 * N_EDGES);
    for (int i = beg + t; i < end; i += 1024) {
        const int idx = (i < N_EDGES) ? dst1[i] : (N_NODES + dst2[i - N_EDGES]);
        atomicAdd(&hist[idx >> BIN_SHIFT], 1);
    }
    __syncthreads();
    if (t < NB) counts[t * NBLK + b] = hist[t];
}

// ---------------------------------------------------------------------------
// Scan: bin totals, exclusive scan over bins, in-place rewrite counts ->
// per-(bin,blk) start cursors. One 512-thread block.
// ---------------------------------------------------------------------------
__global__ __launch_bounds__(512) void k_scan_bins(
    int* __restrict__ counts, int* __restrict__ binStart, int* __restrict__ off)
{
    __shared__ int tot[512];
    const int t = threadIdx.x;
    int total = 0;
    if (t < NB) {
        const int4* p = reinterpret_cast<const int4*>(counts + t * NBLK);
        #pragma unroll 8
        for (int i = 0; i < NBLK / 4; ++i) {
            const int4 c = p[i];
            total += (c.x + c.y) + (c.z + c.w);
        }
    }
    tot[t] = (t < NB) ? total : 0;
    __syncthreads();
    const int v = tot[t];
    for (int d = 1; d < 512; d <<= 1) {
        const int x = (t >= d) ? tot[t - d] : 0;
        __syncthreads();
        tot[t] += x;
        __syncthreads();
    }
    const int excl = tot[t] - v;
    if (t < NB) binStart[t] = excl;
    if (t == NB - 1) binStart[NB] = tot[t];      // == 2*N_EDGES
    if (t == 0) off[N2] = 2 * N_EDGES;           // CSR sentinel
    if (t < NB) {
        int run = excl;
        int* p = counts + t * NBLK;
        for (int i = 0; i < NBLK; i += 4) {
            int4 c = *reinterpret_cast<int4*>(p + i);
            int4 w;
            w.x = run; run += c.x;
            w.y = run; run += c.y;
            w.z = run; run += c.z;
            w.w = run; run += c.w;
            *reinterpret_cast<int4*>(p + i) = w;
        }
    }
}

// ---------------------------------------------------------------------------
// P2: scatter packed records into per-(bin,blk) contiguous sub-ranges.
// rec = (src << 8) | localDst
// ---------------------------------------------------------------------------
__global__ __launch_bounds__(1024) void k_p2_scatter(
    const int* __restrict__ src1, const int* __restrict__ dst1,
    const int* __restrict__ src2, const int* __restrict__ dst2,
    const int* __restrict__ counts, unsigned* __restrict__ binned)
{
    __shared__ int cur[NB];
    const int t = threadIdx.x, b = blockIdx.x;
    if (t < NB) cur[t] = counts[t * NBLK + b];
    __syncthreads();
    const int beg = b * CHUNK;
    const int end = min(beg + CHUNK, 2 * N_EDGES);
    for (int i = beg + t; i < end; i += 1024) {
        int s, idx;
        if (i < N_EDGES) { s = src1[i]; idx = dst1[i]; }
        else             { s = src2[i - N_EDGES]; idx = N_NODES + dst2[i - N_EDGES]; }
        const int bin = idx >> BIN_SHIFT;
        const unsigned rec = ((unsigned)s << BIN_SHIFT) | (unsigned)(idx & (BIN_SZ - 1));
        const int pos = atomicAdd(&cur[bin], 1);
        binned[pos] = rec;
    }
}

// ---------------------------------------------------------------------------
// P3: per-bin CSR build. LDS hist(256) + scan -> off; scatter srcs.
// ---------------------------------------------------------------------------
__global__ __launch_bounds__(1024) void k_p3_csr(
    const unsigned* __restrict__ binned, const int* __restrict__ binStart,
    int* __restrict__ off, int* __restrict__ csr)
{
    __shared__ int hist[BIN_SZ], sc[BIN_SZ], cur[BIN_SZ];
    const int t = threadIdx.x, bin = blockIdx.x;
    const int bs = binStart[bin], be = binStart[bin + 1];
    const int base = bin << BIN_SHIFT;
    const int nloc = min(BIN_SZ, N2 - base);
    if (t < BIN_SZ) hist[t] = 0;
    __syncthreads();
    for (int p = bs + t; p < be; p += 1024)
        atomicAdd(&hist[binned[p] & (BIN_SZ - 1u)], 1);
    __syncthreads();
    int v = 0;
    if (t < BIN_SZ) { v = hist[t]; sc[t] = v; }
    __syncthreads();
    for (int d = 1; d < BIN_SZ; d <<= 1) {
        int x = 0;
        if (t < BIN_SZ && t >= d) x = sc[t - d];
        __syncthreads();
        if (t < BIN_SZ) sc[t] += x;
        __syncthreads();
    }
    if (t < BIN_SZ) {
        const int excl = sc[t] - v;
        cur[t] = bs + excl;
        if (t < nloc) off[base + t] = bs + excl;
    }
    __syncthreads();
    for (int p = bs + t; p < be; p += 1024) {
        const unsigned rec = binned[p];
        const int pos = atomicAdd(&cur[rec & (BIN_SZ - 1u)], 1);
        csr[pos] = (int)(rec >> BIN_SHIFT);
    }
}

// ---------------------------------------------------------------------------
// GEMM 1 (MFMA): y1q = bf16( f @ W1^T ), QUARTER-TILED output
// y1q[q][node][32], q = dim>>5 — each quarter is a contiguous 3.2 MB slab.
// ---------------------------------------------------------------------------
__global__ __launch_bounds__(256) void k_gemm1(
    const float* __restrict__ f, const float* __restrict__ W1,
    unsigned short* __restrict__ y1q)
{
    __shared__ unsigned short Wl[HIDDEN][140];
    const int t = threadIdx.x;
    for (int i = t * 4; i < HIDDEN * IN_DIM; i += 1024) {
        const float4 w = *reinterpret_cast<const float4*>(W1 + i);
        const int o = i >> 7, k = i & 127;
        uint2 p;
        p.x = pack_bf2(w.x, w.y);
        p.y = pack_bf2(w.z, w.w);
        *reinterpret_cast<uint2*>(&Wl[o][k]) = p;
    }
    __syncthreads();

    const int wv = t >> 6;
    const int l  = t & 63;
    const int rc = l & 15;     // A-row / B-col / D-col
    const int kq = l >> 4;     // k-oct selector

    const int sid0 = (blockIdx.x * 4 + wv) * 2;
    const int sid1 = sid0 + 1;
    const bool v0 = sid0 < NSTRIP, v1 = sid1 < NSTRIP;
    const int m0 = min(sid0, NSTRIP - 1) * 16;
    const int m1 = min(sid1, NSTRIP - 1) * 16;

    f32x4 acc[2][8];
    #pragma unroll
    for (int st = 0; st < 2; ++st)
        #pragma unroll
        for (int nt = 0; nt < 8; ++nt)
            acc[st][nt] = (f32x4){0.f, 0.f, 0.f, 0.f};

    #pragma unroll
    for (int kc = 0; kc < 4; ++kc) {
        const int kbase = kc * 32 + kq * 8;
        const float* ap0 = f + (size_t)(m0 + rc) * IN_DIM + kbase;
        const float* ap1 = f + (size_t)(m1 + rc) * IN_DIM + kbase;
        const float4 fa0 = *reinterpret_cast<const float4*>(ap0);
        const float4 fa1 = *reinterpret_cast<const float4*>(ap0 + 4);
        const float4 fb0 = *reinterpret_cast<const float4*>(ap1);
        const float4 fb1 = *reinterpret_cast<const float4*>(ap1 + 4);
        FragU A0, A1;
        A0.u4.x = pack_bf2(fa0.x, fa0.y); A0.u4.y = pack_bf2(fa0.z, fa0.w);
        A0.u4.z = pack_bf2(fa1.x, fa1.y); A0.u4.w = pack_bf2(fa1.z, fa1.w);
        A1.u4.x = pack_bf2(fb0.x, fb0.y); A1.u4.y = pack_bf2(fb0.z, fb0.w);
        A1.u4.z = pack_bf2(fb1.x, fb1.y); A1.u4.w = pack_bf2(fb1.z, fb1.w);
        #pragma unroll
        for (int nt = 0; nt < 8; ++nt) {
            const unsigned short* bp = &Wl[nt * 16 + rc][kbase];
            FragU B;
            B.u2[0] = *reinterpret_cast<const uint2*>(bp);
            B.u2[1] = *reinterpret_cast<const uint2*>(bp + 4);
            acc[0][nt] = __builtin_amdgcn_mfma_f32_16x16x32_bf16(A0.f, B.f, acc[0][nt], 0, 0, 0);
            acc[1][nt] = __builtin_amdgcn_mfma_f32_16x16x32_bf16(A1.f, B.f, acc[1][nt], 0, 0, 0);
        }
    }

    #pragma unroll
    for (int st = 0; st < 2; ++st) {
        if (st == 0 ? !v0 : !v1) continue;
        const int mb = (st == 0 ? m0 : m1) + (l >> 4) * 4;
        #pragma unroll
        for (int nt = 0; nt < 8; ++nt) {
            const int q = nt >> 1;
            const int dd = (nt & 1) * 16 + rc;
            #pragma unroll
            for (int r = 0; r < 4; ++r) {
                y1q[(((size_t)q * N_NODES + (mb + r)) << 5) + dd] = bf1(acc[st][nt][r]);
            }
        }
    }
}

// ---------------------------------------------------------------------------
// GEMM 2 (MFMA): y2h = bf16( x1 @ W2^T ), HALF-TILED output
// y2h[h][node][32], h = dim>>5 — each half is a contiguous 3.2 MB slab.
// ---------------------------------------------------------------------------
__global__ __launch_bounds__(256) void k_gemm2(
    const float* __restrict__ x1, const float* __restrict__ W2,
    unsigned short* __restrict__ y2h)
{
    __shared__ unsigned short Wl[CLASSES][140];
    const int t = threadIdx.x;
    for (int i = t * 4; i < CLASSES * IN_DIM; i += 1024) {
        const float4 w = *reinterpret_cast<const float4*>(W2 + i);
        const int o = i >> 7, k = i & 127;
        uint2 p;
        p.x = pack_bf2(w.x, w.y);
        p.y = pack_bf2(w.z, w.w);
        *reinterpret_cast<uint2*>(&Wl[o][k]) = p;
    }
    __syncthreads();

    const int wv = t >> 6;
    const int l  = t & 63;
    const int rc = l & 15;
    const int kq = l >> 4;

    const int sid0 = (blockIdx.x * 4 + wv) * 2;
    const int sid1 = sid0 + 1;
    const bool v0 = sid0 < NSTRIP, v1 = sid1 < NSTRIP;
    const int m0 = min(sid0, NSTRIP - 1) * 16;
    const int m1 = min(sid1, NSTRIP - 1) * 16;

    f32x4 acc[2][4];
    #pragma unroll
    for (int st = 0; st < 2; ++st)
        #pragma unroll
        for (int nt = 0; nt < 4; ++nt)
            acc[st][nt] = (f32x4){0.f, 0.f, 0.f, 0.f};

    #pragma unroll
    for (int kc = 0; kc < 4; ++kc) {
        const int kbase = kc * 32 + kq * 8;
        const float* ap0 = x1 + (size_t)(m0 + rc) * IN_DIM + kbase;
        const float* ap1 = x1 + (size_t)(m1 + rc) * IN_DIM + kbase;
        const float4 fa0 = *reinterpret_cast<const float4*>(ap0);
        const float4 fa1 = *reinterpret_cast<const float4*>(ap0 + 4);
        const float4 fb0 = *reinterpret_cast<const float4*>(ap1);
        const float4 fb1 = *reinterpret_cast<const float4*>(ap1 + 4);
        FragU A0, A1;
        A0.u4.x = pack_bf2(fa0.x, fa0.y); A0.u4.y = pack_bf2(fa0.z, fa0.w);
        A0.u4.z = pack_bf2(fa1.x, fa1.y); A0.u4.w = pack_bf2(fa1.z, fa1.w);
        A1.u4.x = pack_bf2(fb0.x, fb0.y); A1.u4.y = pack_bf2(fb0.z, fb0.w);
        A1.u4.z = pack_bf2(fb1.x, fb1.y); A1.u4.w = pack_bf2(fb1.z, fb1.w);
        #pragma unroll
        for (int nt = 0; nt < 4; ++nt) {
            const unsigned short* bp = &Wl[nt * 16 + rc][kbase];
            FragU B;
            B.u2[0] = *reinterpret_cast<const uint2*>(bp);
            B.u2[1] = *reinterpret_cast<const uint2*>(bp + 4);
            acc[0][nt] = __builtin_amdgcn_mfma_f32_16x16x32_bf16(A0.f, B.f, acc[0][nt], 0, 0, 0);
            acc[1][nt] = __builtin_amdgcn_mfma_f32_16x16x32_bf16(A1.f, B.f, acc[1][nt], 0, 0, 0);
        }
    }

    #pragma unroll
    for (int st = 0; st < 2; ++st) {
        if (st == 0 ? !v0 : !v1) continue;
        const int mb = (st == 0 ? m0 : m1) + (l >> 4) * 4;
        #pragma unroll
        for (int nt = 0; nt < 4; ++nt) {
            const int h = nt >> 1;
            const int dd = (nt & 1) * 16 + rc;
            #pragma unroll
            for (int r = 0; r < 4; ++r) {
                y2h[(((size_t)h * N_NODES + (mb + r)) << 5) + dd] = bf1(acc[st][nt][r]);
            }
        }
    }
}

// ---------------------------------------------------------------------------
// Pull layer 1, quarter-sliced, XCD-affine.
// Block handles 4 nodes of ONE quarter (q = (blockIdx&7)>>1 — pairs of XCDs
// share a quarter; each quarter slab is 3.2 MB -> L2-resident per XCD).
// Wave = 1 node: 8 lanes per edge row-quarter (uint2 = 4 dims), 8 edges in
// flight; reduce over edge slots via 3 shfl_xor levels.
// ---------------------------------------------------------------------------
__global__ __launch_bounds__(256) void k_pull1(
    const unsigned short* __restrict__ y1q,
    const int* __restrict__ off, const int* __restrict__ csr,
    const float* __restrict__ b1, const float* __restrict__ attn,
    float* __restrict__ x1)
{
    const int bid = blockIdx.x;
    const int q = (bid & 7) >> 1;                 // quarter 0..3
    const int ng = (bid >> 3) * 2 + (bid & 1);    // node group 0..12499
    const int lane = threadIdx.x & 63;
    const int v = ng * 4 + (threadIdx.x >> 6);    // node
    const int es = lane >> 3;                     // edge slot 0..7
    const int c4 = (lane & 7) * 4;                // dims [c4,c4+4) of quarter
    const size_t qbase = (size_t)q * N_NODES;

    float4 tot1, tot2;
    #pragma unroll
    for (int g = 0; g < 2; ++g) {
        const int idx = g * N_NODES + v;
        const int beg = off[idx], end_ = off[idx + 1];
        float4 acc = {0.f, 0.f, 0.f, 0.f};
        int j = beg;
        for (; j + 8 <= end_; j += 8) {
            const int s = csr[j + es];
            const uint2 u = *reinterpret_cast<const uint2*>(y1q + (((qbase + s) << 5) + c4));
            acc4(acc, u);
        }
        if (es < end_ - j) {
            const int s = csr[j + es];
            const uint2 u = *reinterpret_cast<const uint2*>(y1q + (((qbase + s) << 5) + c4));
            acc4(acc, u);
        }
        #pragma unroll
        for (int m = 8; m <= 32; m <<= 1) {
            acc.x += __shfl_xor(acc.x, m);
            acc.y += __shfl_xor(acc.y, m);
            acc.z += __shfl_xor(acc.z, m);
            acc.w += __shfl_xor(acc.w, m);
        }
        if (g == 0) tot1 = acc; else tot2 = acc;
    }

    if (lane < 8) {
        const uint2 uy = *reinterpret_cast<const uint2*>(y1q + (((qbase + v) << 5) + c4));
        const float2 ylo = bf2f2(uy.x), yhi = bf2f2(uy.y);
        const float4 bb = *reinterpret_cast<const float4*>(b1 + q * 32 + c4);
        const float a0 = attn[0], a1 = attn[1];
        float4 r;
        r.x = elu_f(a0 * (ylo.x + tot1.x + bb.x)) + elu_f(a1 * (ylo.x + tot2.x + bb.x));
        r.y = elu_f(a0 * (ylo.y + tot1.y + bb.y)) + elu_f(a1 * (ylo.y + tot2.y + bb.y));
        r.z = elu_f(a0 * (yhi.x + tot1.z + bb.z)) + elu_f(a1 * (yhi.x + tot2.z + bb.z));
        r.w = elu_f(a0 * (yhi.y + tot1.w + bb.w)) + elu_f(a1 * (yhi.y + tot2.w + bb.w));
        *reinterpret_cast<float4*>(x1 + (size_t)v * HIDDEN + q * 32 + c4) = r;
    }
}

// ---------------------------------------------------------------------------
// Pull layer 2, half-sliced, XCD-affine (h = (blockIdx&7)>>2; 4 XCDs/half;
// each half slab 3.2 MB). Same wave structure as pull1.
// ---------------------------------------------------------------------------
__global__ __launch_bounds__(256) void k_pull2(
    const unsigned short* __restrict__ y2h,
    const int* __restrict__ off, const int* __restrict__ csr,
    const float* __restrict__ b2, const float* __restrict__ attn,
    float* __restrict__ out)
{
    const int bid = blockIdx.x;
    const int h = (bid & 7) >> 2;                 // half 0..1
    const int ng = (bid >> 3) * 4 + (bid & 3);    // node group 0..12499
    const int lane = threadIdx.x & 63;
    const int v = ng * 4 + (threadIdx.x >> 6);    // node
    const int es = lane >> 3;                     // edge slot 0..7
    const int c4 = (lane & 7) * 4;                // dims [c4,c4+4) of half
    const size_t hbase = (size_t)h * N_NODES;

    float4 tot1, tot2;
    #pragma unroll
    for (int g = 0; g < 2; ++g) {
        const int idx = g * N_NODES + v;
        const int beg = off[idx], end_ = off[idx + 1];
        float4 acc = {0.f, 0.f, 0.f, 0.f};
        int j = beg;
        for (; j + 8 <= end_; j += 8) {
            const int s = csr[j + es];
            const uint2 u = *reinterpret_cast<const uint2*>(y2h + (((hbase + s) << 5) + c4));
            acc4(acc, u);
        }
        if (es < end_ - j) {
            const int s = csr[j + es];
            const uint2 u = *reinterpret_cast<const uint2*>(y2h + (((hbase + s) << 5) + c4));
            acc4(acc, u);
        }
        #pragma unroll
        for (int m = 8; m <= 32; m <<= 1) {
            acc.x += __shfl_xor(acc.x, m);
            acc.y += __shfl_xor(acc.y, m);
            acc.z += __shfl_xor(acc.z, m);
            acc.w += __shfl_xor(acc.w, m);
        }
        if (g == 0) tot1 = acc; else tot2 = acc;
    }

    if (lane < 8) {
        const uint2 uy = *reinterpret_cast<const uint2*>(y2h + (((hbase + v) << 5) + c4));
        const float2 ylo = bf2f2(uy.x), yhi = bf2f2(uy.y);
        const float4 bb = *reinterpret_cast<const float4*>(b2 + h * 32 + c4);
        const float a0 = attn[0], a1 = attn[1];
        float4 r;
        r.x = elu_f(a0 * (ylo.x + tot1.x + bb.x)) + elu_f(a1 * (ylo.x + tot2.x + bb.x));
        r.y = elu_f(a0 * (ylo.y + tot1.y + bb.y)) + elu_f(a1 * (ylo.y + tot2.y + bb.y));
        r.z = elu_f(a0 * (yhi.x + tot1.z + bb.z)) + elu_f(a1 * (yhi.x + tot2.z + bb.z));
        r.w = elu_f(a0 * (yhi.y + tot1.w + bb.w)) + elu_f(a1 * (yhi.y + tot2.w + bb.w));
        *reinterpret_cast<float4*>(out + (size_t)v * CLASSES + h * 32 + c4) = r;
    }
}

extern "C" void kernel_launch(void* const* d_in, const int* in_sizes, int n_in,
                              void* d_out, int out_size, void* d_ws, size_t ws_size,
                              hipStream_t stream)
{
    const float* features = (const float*)d_in[0];
    const float* W1   = (const float*)d_in[1];
    const float* b1   = (const float*)d_in[2];
    const float* W2   = (const float*)d_in[3];
    const float* b2   = (const float*)d_in[4];
    const float* attn = (const float*)d_in[5];
    const int* src1   = (const int*)d_in[6];
    const int* dst1   = (const int*)d_in[7];
    const int* src2   = (const int*)d_in[8];
    const int* dst2   = (const int*)d_in[9];
    float* out = (float*)d_out;

    // workspace layout (segments padded to 16 B multiples)
    float* x1 = (float*)d_ws;                                        // 6.4M f32
    unsigned short* y1q = (unsigned short*)(x1 + (size_t)N_NODES * HIDDEN);   // 6.4M bf16 (quarter-tiled)
    unsigned short* y2h = y1q + (size_t)N_NODES * HIDDEN;            // 3.2M bf16 (half-tiled)
    int* off      = (int*)(y2h + (size_t)N_NODES * CLASSES);         // N2+4 (padded)
    int* binStart = off + (N2 + 4);                                  // NB+1=392
    int* counts   = binStart + 392;                                  // NB*NBLK
    unsigned* binned = (unsigned*)(counts + NB * NBLK);              // 1.6M
    int* csr      = (int*)(binned + 2 * N_EDGES);                    // 1.6M

    // ---- binned CSR build (shared by both layers) ----
    k_p1_count  <<<NBLK, 1024, 0, stream>>>(dst1, dst2, counts);
    k_scan_bins <<<1, 512, 0, stream>>>(counts, binStart, off);
    k_p2_scatter<<<NBLK, 1024, 0, stream>>>(src1, dst1, src2, dst2, counts, binned);
    k_p3_csr    <<<NB, 1024, 0, stream>>>(binned, binStart, off, csr);

    // ---- layer 1 ----
    k_gemm1<<<GBLK, 256, 0, stream>>>(features, W1, y1q);
    k_pull1<<<50000, 256, 0, stream>>>(y1q, off, csr, b1, attn, x1);

    // ---- layer 2 ----
    k_gemm2<<<GBLK, 256, 0, stream>>>(x1, W2, y2h);
    k_pull2<<<25000, 256, 0, stream>>>(y2h, off, csr, b2, attn, out);
}

// Round 12
// 276.253 us; speedup vs baseline: 1.3405x; 1.3405x over previous
//
#include <hip/hip_runtime.h>
#include <math.h>

#define N_NODES 50000
#define N_EDGES 800000
#define IN_DIM 128
#define HIDDEN 128
#define CLASSES 64
#define N2 100000      // concatenated node space: graph1 [0,50000), graph2 [50000,100000)

#define BIN_SHIFT 8    // 256 nodes per bin
#define BIN_SZ 256
#define NB 391         // ceil(100000/256)
#define NBLK 256       // edge-partition blocks for P1/P2
#define CHUNK ((2 * N_EDGES + NBLK - 1) / NBLK)

#define NSTRIP 3125    // 50000 / 16 rows per MFMA strip
#define GBLK 391       // ceil(3125 / 8 strips per block)

typedef __attribute__((ext_vector_type(8))) short bf16x8;
typedef __attribute__((ext_vector_type(4))) float f32x4;

union FragU {
    uint4 u4;
    uint2 u2[2];
    bf16x8 f;
};

static __device__ __forceinline__ float elu_f(float x) {
    return x > 0.f ? x : (expf(x) - 1.f);
}

// f32 -> bf16 (RNE) pack of two values into one uint (lo = first)
static __device__ __forceinline__ unsigned pack_bf2(float a, float b) {
    unsigned ua = __float_as_uint(a);
    ua = (ua + 0x7FFFu + ((ua >> 16) & 1u)) >> 16;
    unsigned ub = __float_as_uint(b);
    ub = (ub + 0x7FFFu + ((ub >> 16) & 1u)) >> 16;
    return ua | (ub << 16);
}

static __device__ __forceinline__ unsigned short bf1(float x) {
    unsigned u = __float_as_uint(x);
    u = (u + 0x7FFFu + ((u >> 16) & 1u)) >> 16;
    return (unsigned short)u;
}

// unpack two bf16 (packed in uint) -> float2
static __device__ __forceinline__ float2 bf2f2(unsigned u) {
    float2 r;
    r.x = __uint_as_float(u << 16);
    r.y = __uint_as_float(u & 0xFFFF0000u);
    return r;
}

// accumulate 4 bf16 dims (uint2) into float4
static __device__ __forceinline__ void acc4(float4& a, const uint2 u) {
    const float2 lo = bf2f2(u.x);
    const float2 hi = bf2f2(u.y);
    a.x += lo.x; a.y += lo.y; a.z += hi.x; a.w += hi.y;
}

// ---------------------------------------------------------------------------
// P1: per-block LDS histogram over bins. counts[bin*NBLK + blk] (bin-major).
// ---------------------------------------------------------------------------
__global__ __launch_bounds__(1024) void k_p1_count(
    const int* __restrict__ dst1, const int* __restrict__ dst2,
    int* __restrict__ counts)
{
    __shared__ int hist[NB];
    const int t = threadIdx.x, b = blockIdx.x;
    if (t < NB) hist[t] = 0;
    __syncthreads();
    const int beg = b * CHUNK;
    const int end = min(beg + CHUNK, 2 * N_EDGES);
    for (int i = beg + t; i < end; i += 1024) {
        const int idx = (i < N_EDGES) ? dst1[i] : (N_NODES + dst2[i - N_EDGES]);
        atomicAdd(&hist[idx >> BIN_SHIFT], 1);
    }
    __syncthreads();
    if (t < NB) counts[t * NBLK + b] = hist[t];
}

// ---------------------------------------------------------------------------
// Scan: bin totals, exclusive scan over bins, in-place rewrite counts ->
// per-(bin,blk) start cursors. One 512-thread block.
// ---------------------------------------------------------------------------
__global__ __launch_bounds__(512) void k_scan_bins(
    int* __restrict__ counts, int* __restrict__ binStart, int* __restrict__ off)
{
    __shared__ int tot[512];
    const int t = threadIdx.x;
    int total = 0;
    if (t < NB) {
        const int4* p = reinterpret_cast<const int4*>(counts + t * NBLK);
        #pragma unroll 8
        for (int i = 0; i < NBLK / 4; ++i) {
            const int4 c = p[i];
            total += (c.x + c.y) + (c.z + c.w);
        }
    }
    tot[t] = (t < NB) ? total : 0;
    __syncthreads();
    const int v = tot[t];
    for (int d = 1; d < 512; d <<= 1) {
        const int x = (t >= d) ? tot[t - d] : 0;
        __syncthreads();
        tot[t] += x;
        __syncthreads();
    }
    const int excl = tot[t] - v;
    if (t < NB) binStart[t] = excl;
    if (t == NB - 1) binStart[NB] = tot[t];      // == 2*N_EDGES
    if (t == 0) off[N2] = 2 * N_EDGES;           // CSR sentinel
    if (t < NB) {
        int run = excl;
        int* p = counts + t * NBLK;
        for (int i = 0; i < NBLK; i += 4) {
            int4 c = *reinterpret_cast<int4*>(p + i);
            int4 w;
            w.x = run; run += c.x;
            w.y = run; run += c.y;
            w.z = run; run += c.z;
            w.w = run; run += c.w;
            *reinterpret_cast<int4*>(p + i) = w;
        }
    }
}

// ---------------------------------------------------------------------------
// P2: scatter packed records into per-(bin,blk) contiguous sub-ranges.
// rec = (src << 8) | localDst
// ---------------------------------------------------------------------------
__global__ __launch_bounds__(1024) void k_p2_scatter(
    const int* __restrict__ src1, const int* __restrict__ dst1,
    const int* __restrict__ src2, const int* __restrict__ dst2,
    const int* __restrict__ counts, unsigned* __restrict__ binned)
{
    __shared__ int cur[NB];
    const int t = threadIdx.x, b = blockIdx.x;
    if (t < NB) cur[t] = counts[t * NBLK + b];
    __syncthreads();
    const int beg = b * CHUNK;
    const int end = min(beg + CHUNK, 2 * N_EDGES);
    for (int i = beg + t; i < end; i += 1024) {
        int s, idx;
        if (i < N_EDGES) { s = src1[i]; idx = dst1[i]; }
        else             { s = src2[i - N_EDGES]; idx = N_NODES + dst2[i - N_EDGES]; }
        const int bin = idx >> BIN_SHIFT;
        const unsigned rec = ((unsigned)s << BIN_SHIFT) | (unsigned)(idx & (BIN_SZ - 1));
        const int pos = atomicAdd(&cur[bin], 1);
        binned[pos] = rec;
    }
}

// ---------------------------------------------------------------------------
// P3: per-bin CSR build. LDS hist(256) + scan -> off; scatter srcs.
// ---------------------------------------------------------------------------
__global__ __launch_bounds__(1024) void k_p3_csr(
    const unsigned* __restrict__ binned, const int* __restrict__ binStart,
    int* __restrict__ off, int* __restrict__ csr)
{
    __shared__ int hist[BIN_SZ], sc[BIN_SZ], cur[BIN_SZ];
    const int t = threadIdx.x, bin = blockIdx.x;
    const int bs = binStart[bin], be = binStart[bin + 1];
    const int base = bin << BIN_SHIFT;
    const int nloc = min(BIN_SZ, N2 - base);
    if (t < BIN_SZ) hist[t] = 0;
    __syncthreads();
    for (int p = bs + t; p < be; p += 1024)
        atomicAdd(&hist[binned[p] & (BIN_SZ - 1u)], 1);
    __syncthreads();
    int v = 0;
    if (t < BIN_SZ) { v = hist[t]; sc[t] = v; }
    __syncthreads();
    for (int d = 1; d < BIN_SZ; d <<= 1) {
        int x = 0;
        if (t < BIN_SZ && t >= d) x = sc[t - d];
        __syncthreads();
        if (t < BIN_SZ) sc[t] += x;
        __syncthreads();
    }
    if (t < BIN_SZ) {
        const int excl = sc[t] - v;
        cur[t] = bs + excl;
        if (t < nloc) off[base + t] = bs + excl;
    }
    __syncthreads();
    for (int p = bs + t; p < be; p += 1024) {
        const unsigned rec = binned[p];
        const int pos = atomicAdd(&cur[rec & (BIN_SZ - 1u)], 1);
        csr[pos] = (int)(rec >> BIN_SHIFT);
    }
}

// ---------------------------------------------------------------------------
// GEMM 1 (MFMA): y1q = bf16( f @ W1^T ), QUARTER-TILED output
// y1q[q][node][32], q = dim>>5 — each quarter is a contiguous 3.2 MB slab.
// ---------------------------------------------------------------------------
__global__ __launch_bounds__(256) void k_gemm1(
    const float* __restrict__ f, const float* __restrict__ W1,
    unsigned short* __restrict__ y1q)
{
    __shared__ unsigned short Wl[HIDDEN][140];
    const int t = threadIdx.x;
    for (int i = t * 4; i < HIDDEN * IN_DIM; i += 1024) {
        const float4 w = *reinterpret_cast<const float4*>(W1 + i);
        const int o = i >> 7, k = i & 127;
        uint2 p;
        p.x = pack_bf2(w.x, w.y);
        p.y = pack_bf2(w.z, w.w);
        *reinterpret_cast<uint2*>(&Wl[o][k]) = p;
    }
    __syncthreads();

    const int wv = t >> 6;
    const int l  = t & 63;
    const int rc = l & 15;     // A-row / B-col / D-col
    const int kq = l >> 4;     // k-oct selector

    const int sid0 = (blockIdx.x * 4 + wv) * 2;
    const int sid1 = sid0 + 1;
    const bool v0 = sid0 < NSTRIP, v1 = sid1 < NSTRIP;
    const int m0 = min(sid0, NSTRIP - 1) * 16;
    const int m1 = min(sid1, NSTRIP - 1) * 16;

    f32x4 acc[2][8];
    #pragma unroll
    for (int st = 0; st < 2; ++st)
        #pragma unroll
        for (int nt = 0; nt < 8; ++nt)
            acc[st][nt] = (f32x4){0.f, 0.f, 0.f, 0.f};

    #pragma unroll
    for (int kc = 0; kc < 4; ++kc) {
        const int kbase = kc * 32 + kq * 8;
        const float* ap0 = f + (size_t)(m0 + rc) * IN_DIM + kbase;
        const float* ap1 = f + (size_t)(m1 + rc) * IN_DIM + kbase;
        const float4 fa0 = *reinterpret_cast<const float4*>(ap0);
        const float4 fa1 = *reinterpret_cast<const float4*>(ap0 + 4);
        const float4 fb0 = *reinterpret_cast<const float4*>(ap1);
        const float4 fb1 = *reinterpret_cast<const float4*>(ap1 + 4);
        FragU A0, A1;
        A0.u4.x = pack_bf2(fa0.x, fa0.y); A0.u4.y = pack_bf2(fa0.z, fa0.w);
        A0.u4.z = pack_bf2(fa1.x, fa1.y); A0.u4.w = pack_bf2(fa1.z, fa1.w);
        A1.u4.x = pack_bf2(fb0.x, fb0.y); A1.u4.y = pack_bf2(fb0.z, fb0.w);
        A1.u4.z = pack_bf2(fb1.x, fb1.y); A1.u4.w = pack_bf2(fb1.z, fb1.w);
        #pragma unroll
        for (int nt = 0; nt < 8; ++nt) {
            const unsigned short* bp = &Wl[nt * 16 + rc][kbase];
            FragU B;
            B.u2[0] = *reinterpret_cast<const uint2*>(bp);
            B.u2[1] = *reinterpret_cast<const uint2*>(bp + 4);
            acc[0][nt] = __builtin_amdgcn_mfma_f32_16x16x32_bf16(A0.f, B.f, acc[0][nt], 0, 0, 0);
            acc[1][nt] = __builtin_amdgcn_mfma_f32_16x16x32_bf16(A1.f, B.f, acc[1][nt], 0, 0, 0);
        }
    }

    #pragma unroll
    for (int st = 0; st < 2; ++st) {
        if (st == 0 ? !v0 : !v1) continue;
        const int mb = (st == 0 ? m0 : m1) + (l >> 4) * 4;
        #pragma unroll
        for (int nt = 0; nt < 8; ++nt) {
            const int q = nt >> 1;
            const int dd = (nt & 1) * 16 + rc;
            #pragma unroll
            for (int r = 0; r < 4; ++r) {
                y1q[(((size_t)q * N_NODES + (mb + r)) << 5) + dd] = bf1(acc[st][nt][r]);
            }
        }
    }
}

// ---------------------------------------------------------------------------
// GEMM 2 (MFMA): y2h = bf16( x1 @ W2^T ), HALF-TILED output
// y2h[h][node][32], h = dim>>5 — each half is a contiguous 3.2 MB slab.
// ---------------------------------------------------------------------------
__global__ __launch_bounds__(256) void k_gemm2(
    const float* __restrict__ x1, const float* __restrict__ W2,
    unsigned short* __restrict__ y2h)
{
    __shared__ unsigned short Wl[CLASSES][140];
    const int t = threadIdx.x;
    for (int i = t * 4; i < CLASSES * IN_DIM; i += 1024) {
        const float4 w = *reinterpret_cast<const float4*>(W2 + i);
        const int o = i >> 7, k = i & 127;
        uint2 p;
        p.x = pack_bf2(w.x, w.y);
        p.y = pack_bf2(w.z, w.w);
        *reinterpret_cast<uint2*>(&Wl[o][k]) = p;
    }
    __syncthreads();

    const int wv = t >> 6;
    const int l  = t & 63;
    const int rc = l & 15;
    const int kq = l >> 4;

    const int sid0 = (blockIdx.x * 4 + wv) * 2;
    const int sid1 = sid0 + 1;
    const bool v0 = sid0 < NSTRIP, v1 = sid1 < NSTRIP;
    const int m0 = min(sid0, NSTRIP - 1) * 16;
    const int m1 = min(sid1, NSTRIP - 1) * 16;

    f32x4 acc[2][4];
    #pragma unroll
    for (int st = 0; st < 2; ++st)
        #pragma unroll
        for (int nt = 0; nt < 4; ++nt)
            acc[st][nt] = (f32x4){0.f, 0.f, 0.f, 0.f};

    #pragma unroll
    for (int kc = 0; kc < 4; ++kc) {
        const int kbase = kc * 32 + kq * 8;
        const float* ap0 = x1 + (size_t)(m0 + rc) * IN_DIM + kbase;
        const float* ap1 = x1 + (size_t)(m1 + rc) * IN_DIM + kbase;
        const float4 fa0 = *reinterpret_cast<const float4*>(ap0);
        const float4 fa1 = *reinterpret_cast<const float4*>(ap0 + 4);
        const float4 fb0 = *reinterpret_cast<const float4*>(ap1);
        const float4 fb1 = *reinterpret_cast<const float4*>(ap1 + 4);
        FragU A0, A1;
        A0.u4.x = pack_bf2(fa0.x, fa0.y); A0.u4.y = pack_bf2(fa0.z, fa0.w);
        A0.u4.z = pack_bf2(fa1.x, fa1.y); A0.u4.w = pack_bf2(fa1.z, fa1.w);
        A1.u4.x = pack_bf2(fb0.x, fb0.y); A1.u4.y = pack_bf2(fb0.z, fb0.w);
        A1.u4.z = pack_bf2(fb1.x, fb1.y); A1.u4.w = pack_bf2(fb1.z, fb1.w);
        #pragma unroll
        for (int nt = 0; nt < 4; ++nt) {
            const unsigned short* bp = &Wl[nt * 16 + rc][kbase];
            FragU B;
            B.u2[0] = *reinterpret_cast<const uint2*>(bp);
            B.u2[1] = *reinterpret_cast<const uint2*>(bp + 4);
            acc[0][nt] = __builtin_amdgcn_mfma_f32_16x16x32_bf16(A0.f, B.f, acc[0][nt], 0, 0, 0);
            acc[1][nt] = __builtin_amdgcn_mfma_f32_16x16x32_bf16(A1.f, B.f, acc[1][nt], 0, 0, 0);
        }
    }

    #pragma unroll
    for (int st = 0; st < 2; ++st) {
        if (st == 0 ? !v0 : !v1) continue;
        const int mb = (st == 0 ? m0 : m1) + (l >> 4) * 4;
        #pragma unroll
        for (int nt = 0; nt < 4; ++nt) {
            const int h = nt >> 1;
            const int dd = (nt & 1) * 16 + rc;
            #pragma unroll
            for (int r = 0; r < 4; ++r) {
                y2h[(((size_t)h * N_NODES + (mb + r)) << 5) + dd] = bf1(acc[st][nt][r]);
            }
        }
    }
}

// ---------------------------------------------------------------------------
// Pull layer 1, quarter-sliced, XCD-affine, lane-group-serial (NO shfls).
// Block = 4 waves = 32 nodes x 1 quarter. Group of 8 lanes = one node's
// 32-dim quarter (uint2/lane); group loops serially over the node's edges,
// 4-wide unrolled (independent loads). Accumulator stays in-lane.
// q = (blockIdx&7)>>1 keeps each 3.2 MB quarter slab on 2 XCDs' L2.
// ---------------------------------------------------------------------------
__global__ __launch_bounds__(256) void k_pull1(
    const unsigned short* __restrict__ y1q,
    const int* __restrict__ off, const int* __restrict__ csr,
    const float* __restrict__ b1, const float* __restrict__ attn,
    float* __restrict__ x1)
{
    const int bid = blockIdx.x;
    const int q = (bid & 7) >> 1;                 // quarter 0..3
    const int nb = (bid >> 3) * 2 + (bid & 1);    // node-block 0..1563
    const int t = threadIdx.x;
    const int lane = t & 63;
    const int grp = lane >> 3;                    // node within wave 0..7
    const int c4 = (lane & 7) * 4;                // dims [c4,c4+4) of quarter
    const int v = nb * 32 + (t >> 6) * 8 + grp;
    if (v >= N_NODES) return;
    const size_t qbase = (size_t)q * N_NODES;

    float4 tot1 = {0.f, 0.f, 0.f, 0.f}, tot2 = {0.f, 0.f, 0.f, 0.f};
    #pragma unroll
    for (int g = 0; g < 2; ++g) {
        const int idx = g * N_NODES + v;
        const int beg = off[idx], end_ = off[idx + 1];
        float4 acc = {0.f, 0.f, 0.f, 0.f};
        int j = beg;
        for (; j + 4 <= end_; j += 4) {
            const int s0 = csr[j], s1 = csr[j + 1], s2 = csr[j + 2], s3 = csr[j + 3];
            const uint2 u0 = *reinterpret_cast<const uint2*>(y1q + (((qbase + s0) << 5) + c4));
            const uint2 u1 = *reinterpret_cast<const uint2*>(y1q + (((qbase + s1) << 5) + c4));
            const uint2 u2 = *reinterpret_cast<const uint2*>(y1q + (((qbase + s2) << 5) + c4));
            const uint2 u3 = *reinterpret_cast<const uint2*>(y1q + (((qbase + s3) << 5) + c4));
            acc4(acc, u0); acc4(acc, u1); acc4(acc, u2); acc4(acc, u3);
        }
        for (; j < end_; ++j) {
            const int s = csr[j];
            const uint2 u = *reinterpret_cast<const uint2*>(y1q + (((qbase + s) << 5) + c4));
            acc4(acc, u);
        }
        if (g == 0) tot1 = acc; else tot2 = acc;
    }

    const uint2 uy = *reinterpret_cast<const uint2*>(y1q + (((qbase + v) << 5) + c4));
    const float2 ylo = bf2f2(uy.x), yhi = bf2f2(uy.y);
    const float4 bb = *reinterpret_cast<const float4*>(b1 + q * 32 + c4);
    const float a0 = attn[0], a1 = attn[1];
    float4 r;
    r.x = elu_f(a0 * (ylo.x + tot1.x + bb.x)) + elu_f(a1 * (ylo.x + tot2.x + bb.x));
    r.y = elu_f(a0 * (ylo.y + tot1.y + bb.y)) + elu_f(a1 * (ylo.y + tot2.y + bb.y));
    r.z = elu_f(a0 * (yhi.x + tot1.z + bb.z)) + elu_f(a1 * (yhi.x + tot2.z + bb.z));
    r.w = elu_f(a0 * (yhi.y + tot1.w + bb.w)) + elu_f(a1 * (yhi.y + tot2.w + bb.w));
    *reinterpret_cast<float4*>(x1 + (size_t)v * HIDDEN + q * 32 + c4) = r;
}

// ---------------------------------------------------------------------------
// Pull layer 2, half-sliced, XCD-affine, lane-group-serial (NO shfls).
// h = (blockIdx&7)>>2 — each 3.2 MB half slab on 4 XCDs' L2.
// ---------------------------------------------------------------------------
__global__ __launch_bounds__(256) void k_pull2(
    const unsigned short* __restrict__ y2h,
    const int* __restrict__ off, const int* __restrict__ csr,
    const float* __restrict__ b2, const float* __restrict__ attn,
    float* __restrict__ out)
{
    const int bid = blockIdx.x;
    const int h = (bid & 7) >> 2;                 // half 0..1
    const int nb = (bid >> 3) * 4 + (bid & 3);    // node-block 0..1563
    const int t = threadIdx.x;
    const int lane = t & 63;
    const int grp = lane >> 3;                    // node within wave 0..7
    const int c4 = (lane & 7) * 4;                // dims [c4,c4+4) of half
    const int v = nb * 32 + (t >> 6) * 8 + grp;
    if (v >= N_NODES) return;
    const size_t hbase = (size_t)h * N_NODES;

    float4 tot1 = {0.f, 0.f, 0.f, 0.f}, tot2 = {0.f, 0.f, 0.f, 0.f};
    #pragma unroll
    for (int g = 0; g < 2; ++g) {
        const int idx = g * N_NODES + v;
        const int beg = off[idx], end_ = off[idx + 1];
        float4 acc = {0.f, 0.f, 0.f, 0.f};
        int j = beg;
        for (; j + 4 <= end_; j += 4) {
            const int s0 = csr[j], s1 = csr[j + 1], s2 = csr[j + 2], s3 = csr[j + 3];
            const uint2 u0 = *reinterpret_cast<const uint2*>(y2h + (((hbase + s0) << 5) + c4));
            const uint2 u1 = *reinterpret_cast<const uint2*>(y2h + (((hbase + s1) << 5) + c4));
            const uint2 u2 = *reinterpret_cast<const uint2*>(y2h + (((hbase + s2) << 5) + c4));
            const uint2 u3 = *reinterpret_cast<const uint2*>(y2h + (((hbase + s3) << 5) + c4));
            acc4(acc, u0); acc4(acc, u1); acc4(acc, u2); acc4(acc, u3);
        }
        for (; j < end_; ++j) {
            const int s = csr[j];
            const uint2 u = *reinterpret_cast<const uint2*>(y2h + (((hbase + s) << 5) + c4));
            acc4(acc, u);
        }
        if (g == 0) tot1 = acc; else tot2 = acc;
    }

    const uint2 uy = *reinterpret_cast<const uint2*>(y2h + (((hbase + v) << 5) + c4));
    const float2 ylo = bf2f2(uy.x), yhi = bf2f2(uy.y);
    const float4 bb = *reinterpret_cast<const float4*>(b2 + h * 32 + c4);
    const float a0 = attn[0], a1 = attn[1];
    float4 r;
    r.x = elu_f(a0 * (ylo.x + tot1.x + bb.x)) + elu_f(a1 * (ylo.x + tot2.x + bb.x));
    r.y = elu_f(a0 * (ylo.y + tot1.y + bb.y)) + elu_f(a1 * (ylo.y + tot2.y + bb.y));
    r.z = elu_f(a0 * (yhi.x + tot1.z + bb.z)) + elu_f(a1 * (yhi.x + tot2.z + bb.z));
    r.w = elu_f(a0 * (yhi.y + tot1.w + bb.w)) + elu_f(a1 * (yhi.y + tot2.w + bb.w));
    *reinterpret_cast<float4*>(out + (size_t)v * CLASSES + h * 32 + c4) = r;
}

extern "C" void kernel_launch(void* const* d_in, const int* in_sizes, int n_in,
                              void* d_out, int out_size, void* d_ws, size_t ws_size,
                              hipStream_t stream)
{
    const float* features = (const float*)d_in[0];
    const float* W1   = (const float*)d_in[1];
    const float* b1   = (const float*)d_in[2];
    const float* W2   = (const float*)d_in[3];
    const float* b2   = (const float*)d_in[4];
    const float* attn = (const float*)d_in[5];
    const int* src1   = (const int*)d_in[6];
    const int* dst1   = (const int*)d_in[7];
    const int* src2   = (const int*)d_in[8];
    const int* dst2   = (const int*)d_in[9];
    float* out = (float*)d_out;

    // workspace layout (segments padded to 16 B multiples)
    float* x1 = (float*)d_ws;                                        // 6.4M f32
    unsigned short* y1q = (unsigned short*)(x1 + (size_t)N_NODES * HIDDEN);   // 6.4M bf16 (quarter-tiled)
    unsigned short* y2h = y1q + (size_t)N_NODES * HIDDEN;            // 3.2M bf16 (half-tiled)
    int* off      = (int*)(y2h + (size_t)N_NODES * CLASSES);         // N2+4 (padded)
    int* binStart = off + (N2 + 4);                                  // NB+1=392
    int* counts   = binStart + 392;                                  // NB*NBLK
    unsigned* binned = (unsigned*)(counts + NB * NBLK);              // 1.6M
    int* csr      = (int*)(binned + 2 * N_EDGES);                    // 1.6M

    // ---- binned CSR build (shared by both layers) ----
    k_p1_count  <<<NBLK, 1024, 0, stream>>>(dst1, dst2, counts);
    k_scan_bins <<<1, 512, 0, stream>>>(counts, binStart, off);
    k_p2_scatter<<<NBLK, 1024, 0, stream>>>(src1, dst1, src2, dst2, counts, binned);
    k_p3_csr    <<<NB, 1024, 0, stream>>>(binned, binStart, off, csr);

    // ---- layer 1 ----
    k_gemm1<<<GBLK, 256, 0, stream>>>(features, W1, y1q);
    k_pull1<<<6256, 256, 0, stream>>>(y1q, off, csr, b1, attn, x1);

    // ---- layer 2 ----
    k_gemm2<<<GBLK, 256, 0, stream>>>(x1, W2, y2h);
    k_pull2<<<3128, 256, 0, stream>>>(y2h, off, csr, b2, attn, out);
}